// Round 8
// baseline (560.788 us; speedup 1.0000x reference)
//
#include <hip/hip_runtime.h>
#include <math.h>

#define NN 50000
#define NEG 0.2f
#define TILE 4096      // edges per binning block

typedef __attribute__((ext_vector_type(8))) short short8;
typedef __attribute__((ext_vector_type(4))) float f32x4;

__device__ __forceinline__ unsigned short f2bf(float f){
    unsigned u = __float_as_uint(f);
    u += 0x7fffu + ((u >> 16) & 1u);   // round-to-nearest-even
    return (unsigned short)(u >> 16);
}
__device__ __forceinline__ float bf2f(unsigned short v){
    return __uint_as_float(((unsigned)v) << 16);
}

// exclusive scan of 256 values across a 256-thread block
__device__ __forceinline__ int excl_scan_256(int v, int* buf, int tid){
    buf[tid] = v;
    __syncthreads();
#pragma unroll
    for (int off = 1; off < 256; off <<= 1){
        int t = (tid >= off) ? buf[tid - off] : 0;
        __syncthreads();
        buf[tid] += t;
        __syncthreads();
    }
    return buf[tid] - v;
}

// ---------------------- CSR build pass 1: coarse binning (bucket = dst>>8)
__global__ __launch_bounds__(256) void k_binning(const int* __restrict__ ei, int E,
        int* __restrict__ bucketCount, unsigned* __restrict__ tmp){
    __shared__ unsigned stage[TILE];
    __shared__ int hist[256], sbuf[256], exs[256], cur[256], gbase[256];
    int tid = threadIdx.x;
    int EP = E + NN;
    int tileBase = blockIdx.x * TILE;
    int cnt = min(TILE, EP - tileBase);

    hist[tid] = 0;
    __syncthreads();

    unsigned packed[16];
#pragma unroll
    for (int k = 0; k < 16; ++k){
        int e = tileBase + tid + (k << 8);
        unsigned p = 0xffffffffu;
        if (e < EP){
            int s, d;
            if (e < E){ s = ei[e]; d = ei[E + e]; } else { s = e - E; d = s; }
            p = ((unsigned)d << 16) | (unsigned)s;
            atomicAdd(&hist[d >> 8], 1);
        }
        packed[k] = p;
    }
    __syncthreads();
    int h = hist[tid];
    int ex = excl_scan_256(h, sbuf, tid);
    exs[tid] = ex;
    cur[tid] = ex;
    __syncthreads();
#pragma unroll
    for (int k = 0; k < 16; ++k){
        unsigned p = packed[k];
        if (p != 0xffffffffu){
            int b = p >> 24;
            int pos = atomicAdd(&cur[b], 1);
            stage[pos] = p;
        }
    }
    gbase[tid] = atomicAdd(&bucketCount[tid], h);
    __syncthreads();
    for (int i = tid; i < cnt; i += 256){
        unsigned p = stage[i];
        int b = p >> 24;
        tmp[(b << 14) + gbase[b] + (i - exs[b])] = p;
    }
}

// ---------------------- CSR build pass 2: per-bucket fine CSR
__global__ __launch_bounds__(256) void k_bucket_csr(int EP,
        const int* __restrict__ bucketCount, const unsigned* __restrict__ tmp,
        int* __restrict__ row_ptr, unsigned short* __restrict__ ssrc){
    __shared__ int sbuf[256], deg[256], cur[256];
    __shared__ int baseSh, nSh;
    int b = blockIdx.x;
    int tid = threadIdx.x;
    int c = bucketCount[tid];
    int exb = excl_scan_256(c, sbuf, tid);
    if (tid == b){ baseSh = exb; nSh = c; }
    deg[tid] = 0;
    __syncthreads();
    int base = baseSh, n = nSh;
    const unsigned* tb = tmp + ((size_t)b << 14);
    for (int i = tid; i < n; i += 256)
        atomicAdd(&deg[(tb[i] >> 16) & 255], 1);
    __syncthreads();
    int d = deg[tid];
    int dx = excl_scan_256(d, sbuf, tid);
    cur[tid] = dx;
    int dst = (b << 8) + tid;
    if (dst < NN) row_ptr[dst] = base + dx;
    if (b == 0 && tid == 0) row_ptr[NN] = EP;
    __syncthreads();
    for (int i = tid; i < n; i += 256){
        unsigned p = tb[i];
        int pos = atomicAdd(&cur[(p >> 16) & 255], 1);
        ssrc[base + pos] = (unsigned short)(p & 0xffffu);
    }
}

// ------------------------- pack W -> B^T bf16 hi/lo tables (one-shot, tiny)
__global__ void k_packW(const float* __restrict__ W0, const float* __restrict__ W1,
                        const float* __restrict__ W2,
                        unsigned short* __restrict__ h0, unsigned short* __restrict__ l0,
                        unsigned short* __restrict__ h1, unsigned short* __restrict__ l1,
                        unsigned short* __restrict__ h2, unsigned short* __restrict__ l2){
    int t = blockIdx.x * 256 + threadIdx.x;
    const float* W; unsigned short *ph, *pl; int Ncol; int u;
    if (t < 16384){ W = W0; ph = h0; pl = l0; Ncol = 128; u = t; }
    else if (t < 32768){ W = W1; ph = h1; pl = l1; Ncol = 128; u = t - 16384; }
    else if (t < 36864){ W = W2; ph = h2; pl = l2; Ncol = 32;  u = t - 32768; }
    else return;
    int n = u >> 7, k = u & 127;
    float f = W[k * Ncol + n];
    unsigned short hi = f2bf(f);
    unsigned short lo = f2bf(f - bf2f(hi));
    ph[n * 128 + k] = hi;
    pl[n * 128 + k] = lo;
}

// -------------------------------------- MFMA GEMM: C[M,NT*16] = A[M,128]@B
// hi/lo-compensated bf16 (3 MFMAs) ~= fp32 accuracy.
// Cbf (when non-null, Ncol=128) written in [head][node][32ch] bf16 layout.
template<int NT>
__global__ __launch_bounds__(256) void k_gemm_mfma(
        const float* __restrict__ A,
        const unsigned short* __restrict__ Bhi,   // [NT*16][128] bf16 (B^T)
        const unsigned short* __restrict__ Blo,
        float* __restrict__ C, unsigned short* __restrict__ Cbf, int M){
    const int Ncol = NT * 16;
    int wave = threadIdx.x >> 6;
    int lane = threadIdx.x & 63;
    int r    = lane & 15;
    int oct  = lane >> 4;
    int rowBase = blockIdx.x * 64 + wave * 16;

    f32x4 acc[NT];
#pragma unroll
    for (int c = 0; c < NT; ++c) acc[c] = (f32x4){0.f, 0.f, 0.f, 0.f};

    int lrow = rowBase + r; if (lrow > M - 1) lrow = M - 1;
    const float* arow = A + (size_t)lrow * 128;

    for (int t = 0; t < 4; ++t){
        int k0 = t * 32 + oct * 8;
        float4 a0 = *(const float4*)&arow[k0];
        float4 a1 = *(const float4*)&arow[k0 + 4];
        float av[8] = {a0.x, a0.y, a0.z, a0.w, a1.x, a1.y, a1.z, a1.w};
        short8 ahi, alo;
#pragma unroll
        for (int j = 0; j < 8; ++j){
            unsigned short h = f2bf(av[j]);
            unsigned short l = f2bf(av[j] - bf2f(h));
            ahi[j] = (short)h; alo[j] = (short)l;
        }
#pragma unroll
        for (int c = 0; c < NT; ++c){
            short8 bhi = *(const short8*)&Bhi[(c * 16 + r) * 128 + k0];
            short8 blo = *(const short8*)&Blo[(c * 16 + r) * 128 + k0];
            acc[c] = __builtin_amdgcn_mfma_f32_16x16x32_bf16(ahi, bhi, acc[c], 0, 0, 0);
            acc[c] = __builtin_amdgcn_mfma_f32_16x16x32_bf16(alo, bhi, acc[c], 0, 0, 0);
            acc[c] = __builtin_amdgcn_mfma_f32_16x16x32_bf16(ahi, blo, acc[c], 0, 0, 0);
        }
    }
    // C/D layout: col = lane&15, row = oct*4 + reg
#pragma unroll
    for (int c = 0; c < NT; ++c){
#pragma unroll
        for (int reg = 0; reg < 4; ++reg){
            int row = rowBase + oct * 4 + reg;
            if (row < M){
                int col = c * 16 + r;
                float v = acc[c][reg];
                C[(size_t)row * Ncol + col] = v;
                if (Cbf){
                    int head = col >> 5, ch = col & 31;
                    Cbf[((size_t)head * NN + row) * 32 + ch] = f2bf(v);
                }
            }
        }
    }
}

// ------------------------------------------- per-node attention half-logits
__global__ void k_nodealpha(const float* __restrict__ h,
                            const float* __restrict__ a_s,
                            const float* __restrict__ a_d,
                            float* __restrict__ asrc, float* __restrict__ adst,
                            int H, int C){
    int t = blockIdx.x * 256 + threadIdx.x;
    if (t >= NN * H) return;
    int n = t / H, hd = t % H;
    const float* hp = h + (size_t)n * H * C + hd * C;
    float s1 = 0.f, s2 = 0.f;
    for (int c = 0; c < C; c += 4){
        float4 hv = *(const float4*)&hp[c];
        float4 av = *(const float4*)&a_s[hd * C + c];
        float4 dv = *(const float4*)&a_d[hd * C + c];
        s1 += hv.x * av.x + hv.y * av.y + hv.z * av.z + hv.w * av.w;
        s2 += hv.x * dv.x + hv.y * dv.y + hv.z * dv.z + hv.w * dv.w;
    }
    asrc[t] = s1;
    adst[t] = s2;
}

// ---------- HEAD-PHASED single-pass aggregation, 4 heads x 32 ch (bf16 h)
// blockIdx.y = head. Per phase the gather working set is [head][NN][32ch]
// = 3.2 MB < 4 MB per-XCD L2 -> random gathers hit L2 after warmup.
// 16 edge subgroups x 4 channel-lanes; adjacent-pair edges (32 edges/iter).
__global__ __launch_bounds__(256) void k_agg4p(
        const uint4* __restrict__ hb,             // [4][NN][4] uint4 (64B rows)
        const float* __restrict__ asrc, const float* __restrict__ adst,
        const int* __restrict__ row_ptr, const unsigned short* __restrict__ ssrc,
        const float* __restrict__ bias, float* __restrict__ outp,
        float* __restrict__ gdenom, int writeStats){
    int wave = (blockIdx.x * 256 + threadIdx.x) >> 6;
    int lane = threadIdx.x & 63;
    if (wave >= NN) return;
    int i = wave;
    int h = blockIdx.y;                  // head 0..3
    int lo = row_ptr[i], hi = row_ptr[i + 1];
    int g = lane >> 2;                   // edge subgroup 0..15
    int q = lane & 3;                    // channel chunk: ch q*8..q*8+7
    float adv = adst[i * 4 + h];
    const uint4* hbh = hb + (size_t)h * NN * 4;

    float acc[8];
#pragma unroll
    for (int k = 0; k < 8; ++k) acc[k] = 0.f;
    float dsum = 0.f;

#define AGG4_FMA(AA, GV) {                                                    \
        acc[0] += (AA) * __uint_as_float((GV).x << 16);                       \
        acc[1] += (AA) * __uint_as_float((GV).x & 0xffff0000u);               \
        acc[2] += (AA) * __uint_as_float((GV).y << 16);                       \
        acc[3] += (AA) * __uint_as_float((GV).y & 0xffff0000u);               \
        acc[4] += (AA) * __uint_as_float((GV).z << 16);                       \
        acc[5] += (AA) * __uint_as_float((GV).z & 0xffff0000u);               \
        acc[6] += (AA) * __uint_as_float((GV).w << 16);                       \
        acc[7] += (AA) * __uint_as_float((GV).w & 0xffff0000u); }
#define AGG4_ONE(JJ) {                                                        \
        float lg_ = asrc[(JJ) * 4u + h] + adv;                                \
        lg_ = fmaxf(lg_, NEG * lg_);                                          \
        float a_ = __expf(lg_);                                               \
        dsum += a_;                                                           \
        uint4 gv_ = hbh[(JJ) * 4u + (unsigned)q];                             \
        AGG4_FMA(a_, gv_) }

    int idx = lo;
    if (lo & 1){                         // peel to even alignment
        if (g == 0){ unsigned j = ssrc[lo]; AGG4_ONE(j) }
        idx = lo + 1;
    }
    for (; idx + 32 <= hi; idx += 32){
        unsigned pair = *(const unsigned*)&ssrc[idx + 2 * g];   // aligned
        unsigned j0 = pair & 0xffffu, j1 = pair >> 16;
        float s0 = asrc[j0 * 4u + h];
        float s1 = asrc[j1 * 4u + h];
        uint4 gv0 = hbh[j0 * 4u + (unsigned)q];
        uint4 gv1 = hbh[j1 * 4u + (unsigned)q];
        float lg0 = s0 + adv; lg0 = fmaxf(lg0, NEG * lg0);
        float lg1 = s1 + adv; lg1 = fmaxf(lg1, NEG * lg1);
        float a0 = __expf(lg0), a1 = __expf(lg1);
        dsum += a0 + a1;
        AGG4_FMA(a0, gv0)
        AGG4_FMA(a1, gv1)
    }
    {   // remainder < 32 edges
        int k0 = idx + 2 * g, k1 = k0 + 1;
        if (k0 < hi){ unsigned j = ssrc[k0]; AGG4_ONE(j) }
        if (k1 < hi){ unsigned j = ssrc[k1]; AGG4_ONE(j) }
    }
#undef AGG4_ONE
#undef AGG4_FMA
    // combine the 16 edge subgroups (lane bits 2..5), q stays fixed
#pragma unroll
    for (int k = 0; k < 8; ++k){
        acc[k] += __shfl_xor(acc[k], 4);
        acc[k] += __shfl_xor(acc[k], 8);
        acc[k] += __shfl_xor(acc[k], 16);
        acc[k] += __shfl_xor(acc[k], 32);
    }
    dsum += __shfl_xor(dsum, 4);
    dsum += __shfl_xor(dsum, 8);
    dsum += __shfl_xor(dsum, 16);
    dsum += __shfl_xor(dsum, 32);

    if (writeStats && g == 0 && q == 0)
        gdenom[i * 4 + h] = dsum;

    if (g == 0){
        float rs = 1.f / dsum;
        int c0 = h * 32 + q * 8;
        float4 bA = *(const float4*)&bias[c0];
        float4 bB = *(const float4*)&bias[c0 + 4];
        float o[8] = {acc[0] * rs + bA.x, acc[1] * rs + bA.y,
                      acc[2] * rs + bA.z, acc[3] * rs + bA.w,
                      acc[4] * rs + bB.x, acc[5] * rs + bB.y,
                      acc[6] * rs + bB.z, acc[7] * rs + bB.w};
#pragma unroll
        for (int k = 0; k < 8; ++k)
            o[k] = (o[k] > 0.f) ? o[k] : (__expf(o[k]) - 1.f);   // ELU
        *(float4*)&outp[(size_t)i * 128 + c0]     = make_float4(o[0], o[1], o[2], o[3]);
        *(float4*)&outp[(size_t)i * 128 + c0 + 4] = make_float4(o[4], o[5], o[6], o[7]);
    }
}

// ------------------------------------ alpha0 in ORIGINAL edge order (layer0)
__global__ void k_alpha0(const int* __restrict__ ei, int E,
                         const float4* __restrict__ asrc4, const float4* __restrict__ adst4,
                         const float4* __restrict__ gd4, float4* __restrict__ out){
    int e = blockIdx.x * 256 + threadIdx.x;
    int EP = E + NN;
    if (e >= EP) return;
    int s, d;
    if (e < E){ s = ei[e]; d = ei[E + e]; } else { s = e - E; d = s; }
    float4 as = asrc4[s], ad = adst4[d], dn = gd4[d];
    float4 r;
    float lg;
    lg = as.x + ad.x; lg = fmaxf(lg, NEG * lg); r.x = __expf(lg) / dn.x;
    lg = as.y + ad.y; lg = fmaxf(lg, NEG * lg); r.y = __expf(lg) / dn.y;
    lg = as.z + ad.z; lg = fmaxf(lg, NEG * lg); r.z = __expf(lg) / dn.z;
    lg = as.w + ad.w; lg = fmaxf(lg, NEG * lg); r.w = __expf(lg) / dn.w;
    out[e] = r;
}

// ---------- HALF-PHASED single-pass aggregation, 1 head x 32 ch (fp32 h)
// blockIdx.y = half (16 channels = 64B): working set 3.2 MB < L2.
// 16 subgroups x 4 channel-lanes; adjacent-pair edges (32 edges/iter).
__global__ __launch_bounds__(256) void k_agg1p(
        const float4* __restrict__ h24,           // [NN][8] float4 rows
        const float* __restrict__ asrc, const float* __restrict__ adst,
        const int* __restrict__ row_ptr, const unsigned short* __restrict__ ssrc,
        const float* __restrict__ bias, float* __restrict__ outp){
    int wave = (blockIdx.x * 256 + threadIdx.x) >> 6;
    int lane = threadIdx.x & 63;
    if (wave >= NN) return;
    int i = wave;
    int p = blockIdx.y;                  // channel half 0..1
    int lo = row_ptr[i], hi = row_ptr[i + 1];
    int g = lane >> 2;                   // edge subgroup 0..15
    int q = lane & 3;                    // channel chunk within half
    unsigned co = (unsigned)(p * 4 + q); // float4 index into row
    float adv = adst[i];

    float acc[4] = {0.f, 0.f, 0.f, 0.f};
    float dsum = 0.f;

#define AGG1_ONE(JJ) {                                                        \
        float lg_ = asrc[(JJ)] + adv;                                         \
        lg_ = fmaxf(lg_, NEG * lg_);                                          \
        float a_ = __expf(lg_);                                               \
        dsum += a_;                                                           \
        float4 v_ = h24[(JJ) * 8u + co];                                      \
        acc[0] += a_ * v_.x; acc[1] += a_ * v_.y;                             \
        acc[2] += a_ * v_.z; acc[3] += a_ * v_.w; }

    int idx = lo;
    if (lo & 1){
        if (g == 0){ unsigned j = ssrc[lo]; AGG1_ONE(j) }
        idx = lo + 1;
    }
    for (; idx + 32 <= hi; idx += 32){
        unsigned pair = *(const unsigned*)&ssrc[idx + 2 * g];
        unsigned j0 = pair & 0xffffu, j1 = pair >> 16;
        float s0 = asrc[j0];
        float s1 = asrc[j1];
        float4 v0 = h24[j0 * 8u + co];
        float4 v1 = h24[j1 * 8u + co];
        float lg0 = s0 + adv; lg0 = fmaxf(lg0, NEG * lg0);
        float lg1 = s1 + adv; lg1 = fmaxf(lg1, NEG * lg1);
        float a0 = __expf(lg0), a1 = __expf(lg1);
        dsum += a0 + a1;
        acc[0] += a0 * v0.x; acc[1] += a0 * v0.y;
        acc[2] += a0 * v0.z; acc[3] += a0 * v0.w;
        acc[0] += a1 * v1.x; acc[1] += a1 * v1.y;
        acc[2] += a1 * v1.z; acc[3] += a1 * v1.w;
    }
    {   // remainder < 32 edges
        int k0 = idx + 2 * g, k1 = k0 + 1;
        if (k0 < hi){ unsigned j = ssrc[k0]; AGG1_ONE(j) }
        if (k1 < hi){ unsigned j = ssrc[k1]; AGG1_ONE(j) }
    }
#undef AGG1_ONE
#pragma unroll
    for (int k = 0; k < 4; ++k){
        acc[k] += __shfl_xor(acc[k], 4);
        acc[k] += __shfl_xor(acc[k], 8);
        acc[k] += __shfl_xor(acc[k], 16);
        acc[k] += __shfl_xor(acc[k], 32);
    }
    dsum += __shfl_xor(dsum, 4);
    dsum += __shfl_xor(dsum, 8);
    dsum += __shfl_xor(dsum, 16);
    dsum += __shfl_xor(dsum, 32);
    if (g == 0){
        float rs = 1.f / dsum;
        float4 b = *(const float4*)&bias[co * 4];
        *(float4*)&outp[(size_t)i * 32 + co * 4] =
            make_float4(acc[0] * rs + b.x, acc[1] * rs + b.y,
                        acc[2] * rs + b.z, acc[3] * rs + b.w);
    }
}

// ---------------------------------------------------------------- launcher
extern "C" void kernel_launch(void* const* d_in, const int* in_sizes, int n_in,
                              void* d_out, int out_size, void* d_ws, size_t ws_size,
                              hipStream_t stream){
    const float* x   = (const float*)d_in[0];
    const int*   ei  = (const int*)  d_in[1];
    const float* W0  = (const float*)d_in[2];
    const float* as0 = (const float*)d_in[3];
    const float* ad0 = (const float*)d_in[4];
    const float* b0  = (const float*)d_in[5];
    const float* W1  = (const float*)d_in[6];
    const float* as1 = (const float*)d_in[7];
    const float* ad1 = (const float*)d_in[8];
    const float* b1  = (const float*)d_in[9];
    const float* W2  = (const float*)d_in[10];
    const float* as2 = (const float*)d_in[11];
    const float* ad2 = (const float*)d_in[12];
    const float* b2  = (const float*)d_in[13];

    const int E  = in_sizes[1] / 2;
    const int EP = E + NN;

    char* w = (char*)d_ws;
    size_t off = 0;
    auto carve = [&](size_t bytes) -> char* {
        char* p = w + off;
        off += (bytes + 255) & ~(size_t)255;
        return p;
    };
    int*            bucketCount = (int*)       carve(sizeof(int) * 256);
    int*            row_ptr = (int*)           carve(sizeof(int) * (NN + 1));
    unsigned short* ssrc    = (unsigned short*)carve(sizeof(short) * ((size_t)EP + 2));
    float*          hbuf    = (float*)         carve(sizeof(float) * (size_t)NN * 128);
    unsigned short* hb16    = (unsigned short*)carve(sizeof(short) * (size_t)NN * 128);
    float*          post    = (float*)         carve(sizeof(float) * (size_t)NN * 128);
    float*          asrc    = (float*)         carve(sizeof(float) * NN * 4);
    float*          adst    = (float*)         carve(sizeof(float) * NN * 4);
    float*          gdenom  = (float*)         carve(sizeof(float) * NN * 4);
    unsigned short* Whi0    = (unsigned short*)carve(sizeof(short) * 16384);
    unsigned short* Wlo0    = (unsigned short*)carve(sizeof(short) * 16384);
    unsigned short* Whi1    = (unsigned short*)carve(sizeof(short) * 16384);
    unsigned short* Wlo1    = (unsigned short*)carve(sizeof(short) * 16384);
    unsigned short* Whi2    = (unsigned short*)carve(sizeof(short) * 4096);
    unsigned short* Wlo2    = (unsigned short*)carve(sizeof(short) * 4096);
    // tmp (16MB) aliases post (25.6MB): consumed by k_bucket_csr before
    // layer-0 agg4p first writes post (stream-ordered).
    unsigned*       tmp     = (unsigned*)post;

    float* out_alpha = (float*)d_out;                  // [EP, 4]
    float* out_final = (float*)d_out + (size_t)EP * 4; // [NN, 32]

    const int edgeBlocks = (EP + 255) / 256;
    const int waveBlocks = (NN + 3) / 4;
    const int gemmBlocks = (NN + 63) / 64;
    const dim3 agg4Grid(waveBlocks, 4);
    const dim3 agg1Grid(waveBlocks, 2);

    // ---- CSR build + weight pack
    hipMemsetAsync(bucketCount, 0, sizeof(int) * 256, stream);
    k_binning   <<<(EP + TILE - 1) / TILE, 256, 0, stream>>>(ei, E, bucketCount, tmp);
    k_bucket_csr<<<256, 256, 0, stream>>>(EP, bucketCount, tmp, row_ptr, ssrc);
    k_packW     <<<144, 256, 0, stream>>>(W0, W1, W2, Whi0, Wlo0, Whi1, Wlo1, Whi2, Wlo2);

    // ---- layer 0
    k_gemm_mfma<8><<<gemmBlocks, 256, 0, stream>>>(x, Whi0, Wlo0, hbuf, hb16, NN);
    k_nodealpha<<<(NN * 4 + 255) / 256, 256, 0, stream>>>(hbuf, as0, ad0, asrc, adst, 4, 32);
    k_agg4p<<<agg4Grid, 256, 0, stream>>>((const uint4*)hb16, asrc, adst, row_ptr,
                                          ssrc, b0, post, gdenom, 1);
    k_alpha0<<<edgeBlocks, 256, 0, stream>>>(ei, E, (const float4*)asrc, (const float4*)adst,
                                             (const float4*)gdenom, (float4*)out_alpha);

    // ---- layer 1
    k_gemm_mfma<8><<<gemmBlocks, 256, 0, stream>>>(post, Whi1, Wlo1, hbuf, hb16, NN);
    k_nodealpha<<<(NN * 4 + 255) / 256, 256, 0, stream>>>(hbuf, as1, ad1, asrc, adst, 4, 32);
    k_agg4p<<<agg4Grid, 256, 0, stream>>>((const uint4*)hb16, asrc, adst, row_ptr,
                                          ssrc, b1, post, gdenom, 0);

    // ---- layer 2 (1 head, 32 out, no concat/ELU)
    k_gemm_mfma<2><<<gemmBlocks, 256, 0, stream>>>(post, Whi2, Wlo2, hbuf, nullptr, NN);
    k_nodealpha<<<(NN + 255) / 256, 256, 0, stream>>>(hbuf, as2, ad2, asrc, adst, 1, 32);
    k_agg1p<<<agg1Grid, 256, 0, stream>>>((const float4*)hbuf, asrc, adst, row_ptr,
                                          ssrc, b2, out_final);
}

// Round 9
// 410.151 us; speedup vs baseline: 1.3673x; 1.3673x over previous
//
#include <hip/hip_runtime.h>
#include <math.h>

#define NN 50000
#define NEG 0.2f
#define TILE 4096      // edges per binning block

typedef __attribute__((ext_vector_type(8))) short short8;
typedef __attribute__((ext_vector_type(4))) float f32x4;

__device__ __forceinline__ unsigned short f2bf(float f){
    unsigned u = __float_as_uint(f);
    u += 0x7fffu + ((u >> 16) & 1u);   // round-to-nearest-even
    return (unsigned short)(u >> 16);
}
__device__ __forceinline__ float bf2f(unsigned short v){
    return __uint_as_float(((unsigned)v) << 16);
}

// exclusive scan of 256 values across a 256-thread block
__device__ __forceinline__ int excl_scan_256(int v, int* buf, int tid){
    buf[tid] = v;
    __syncthreads();
#pragma unroll
    for (int off = 1; off < 256; off <<= 1){
        int t = (tid >= off) ? buf[tid - off] : 0;
        __syncthreads();
        buf[tid] += t;
        __syncthreads();
    }
    return buf[tid] - v;
}

// ---------------------- CSR build pass 1: coarse binning (bucket = dst>>8)
__global__ __launch_bounds__(256) void k_binning(const int* __restrict__ ei, int E,
        int* __restrict__ bucketCount, unsigned* __restrict__ tmp){
    __shared__ unsigned stage[TILE];
    __shared__ int hist[256], sbuf[256], exs[256], cur[256], gbase[256];
    int tid = threadIdx.x;
    int EP = E + NN;
    int tileBase = blockIdx.x * TILE;
    int cnt = min(TILE, EP - tileBase);

    hist[tid] = 0;
    __syncthreads();

    unsigned packed[16];
#pragma unroll
    for (int k = 0; k < 16; ++k){
        int e = tileBase + tid + (k << 8);
        unsigned p = 0xffffffffu;
        if (e < EP){
            int s, d;
            if (e < E){ s = ei[e]; d = ei[E + e]; } else { s = e - E; d = s; }
            p = ((unsigned)d << 16) | (unsigned)s;
            atomicAdd(&hist[d >> 8], 1);
        }
        packed[k] = p;
    }
    __syncthreads();
    int h = hist[tid];
    int ex = excl_scan_256(h, sbuf, tid);
    exs[tid] = ex;
    cur[tid] = ex;
    __syncthreads();
#pragma unroll
    for (int k = 0; k < 16; ++k){
        unsigned p = packed[k];
        if (p != 0xffffffffu){
            int b = p >> 24;
            int pos = atomicAdd(&cur[b], 1);
            stage[pos] = p;
        }
    }
    gbase[tid] = atomicAdd(&bucketCount[tid], h);
    __syncthreads();
    for (int i = tid; i < cnt; i += 256){
        unsigned p = stage[i];
        int b = p >> 24;
        tmp[(b << 14) + gbase[b] + (i - exs[b])] = p;
    }
}

// ---------------------- CSR build pass 2: per-bucket fine CSR
__global__ __launch_bounds__(256) void k_bucket_csr(int EP,
        const int* __restrict__ bucketCount, const unsigned* __restrict__ tmp,
        int* __restrict__ row_ptr, unsigned short* __restrict__ ssrc){
    __shared__ int sbuf[256], deg[256], cur[256];
    __shared__ int baseSh, nSh;
    int b = blockIdx.x;
    int tid = threadIdx.x;
    int c = bucketCount[tid];
    int exb = excl_scan_256(c, sbuf, tid);
    if (tid == b){ baseSh = exb; nSh = c; }
    deg[tid] = 0;
    __syncthreads();
    int base = baseSh, n = nSh;
    const unsigned* tb = tmp + ((size_t)b << 14);
    for (int i = tid; i < n; i += 256)
        atomicAdd(&deg[(tb[i] >> 16) & 255], 1);
    __syncthreads();
    int d = deg[tid];
    int dx = excl_scan_256(d, sbuf, tid);
    cur[tid] = dx;
    int dst = (b << 8) + tid;
    if (dst < NN) row_ptr[dst] = base + dx;
    if (b == 0 && tid == 0) row_ptr[NN] = EP;
    __syncthreads();
    for (int i = tid; i < n; i += 256){
        unsigned p = tb[i];
        int pos = atomicAdd(&cur[(p >> 16) & 255], 1);
        ssrc[base + pos] = (unsigned short)(p & 0xffffu);
    }
}

// ------------------------- pack W -> B^T bf16 hi/lo tables (one-shot, tiny)
__global__ void k_packW(const float* __restrict__ W0, const float* __restrict__ W1,
                        const float* __restrict__ W2,
                        unsigned short* __restrict__ h0, unsigned short* __restrict__ l0,
                        unsigned short* __restrict__ h1, unsigned short* __restrict__ l1,
                        unsigned short* __restrict__ h2, unsigned short* __restrict__ l2){
    int t = blockIdx.x * 256 + threadIdx.x;
    const float* W; unsigned short *ph, *pl; int Ncol; int u;
    if (t < 16384){ W = W0; ph = h0; pl = l0; Ncol = 128; u = t; }
    else if (t < 32768){ W = W1; ph = h1; pl = l1; Ncol = 128; u = t - 16384; }
    else if (t < 36864){ W = W2; ph = h2; pl = l2; Ncol = 32;  u = t - 32768; }
    else return;
    int n = u >> 7, k = u & 127;
    float f = W[k * Ncol + n];
    unsigned short hi = f2bf(f);
    unsigned short lo = f2bf(f - bf2f(hi));
    ph[n * 128 + k] = hi;
    pl[n * 128 + k] = lo;
}

// -------------------------------------- MFMA GEMM: C[M,NT*16] = A[M,128]@B
// hi/lo-compensated bf16 (3 MFMAs) ~= fp32 accuracy.
// FUSED node-alpha epilogue: asrc[n,h]=dot(h[n,h,:],a_s[h,:]), adst likewise.
// head = col>>5 = c>>1 (r-independent) -> per-lane partial over c, then
// 4-level shfl_xor reduce over the 16 r-lanes of each oct group.
// HH = heads (4 for NT=8, 1 for NT=2). C (fp32) and Cbf (bf16) optional.
template<int NT, int HH>
__global__ __launch_bounds__(256) void k_gemm_mfma(
        const float* __restrict__ A,
        const unsigned short* __restrict__ Bhi,   // [NT*16][128] bf16 (B^T)
        const unsigned short* __restrict__ Blo,
        float* __restrict__ C, unsigned short* __restrict__ Cbf,
        const float* __restrict__ a_s,            // [HH*32] flattened
        const float* __restrict__ a_d,
        float* __restrict__ asrc, float* __restrict__ adst, int M){
    const int Ncol = NT * 16;
    int wave = threadIdx.x >> 6;
    int lane = threadIdx.x & 63;
    int r    = lane & 15;
    int oct  = lane >> 4;
    int rowBase = blockIdx.x * 64 + wave * 16;

    f32x4 acc[NT];
#pragma unroll
    for (int c = 0; c < NT; ++c) acc[c] = (f32x4){0.f, 0.f, 0.f, 0.f};

    int lrow = rowBase + r; if (lrow > M - 1) lrow = M - 1;
    const float* arow = A + (size_t)lrow * 128;

    for (int t = 0; t < 4; ++t){
        int k0 = t * 32 + oct * 8;
        float4 a0 = *(const float4*)&arow[k0];
        float4 a1 = *(const float4*)&arow[k0 + 4];
        float av[8] = {a0.x, a0.y, a0.z, a0.w, a1.x, a1.y, a1.z, a1.w};
        short8 ahi, alo;
#pragma unroll
        for (int j = 0; j < 8; ++j){
            unsigned short h = f2bf(av[j]);
            unsigned short l = f2bf(av[j] - bf2f(h));
            ahi[j] = (short)h; alo[j] = (short)l;
        }
#pragma unroll
        for (int c = 0; c < NT; ++c){
            short8 bhi = *(const short8*)&Bhi[(c * 16 + r) * 128 + k0];
            short8 blo = *(const short8*)&Blo[(c * 16 + r) * 128 + k0];
            acc[c] = __builtin_amdgcn_mfma_f32_16x16x32_bf16(ahi, bhi, acc[c], 0, 0, 0);
            acc[c] = __builtin_amdgcn_mfma_f32_16x16x32_bf16(alo, bhi, acc[c], 0, 0, 0);
            acc[c] = __builtin_amdgcn_mfma_f32_16x16x32_bf16(ahi, blo, acc[c], 0, 0, 0);
        }
    }
    // C/D layout: col = lane&15 (=r), row = oct*4 + reg
#pragma unroll
    for (int c = 0; c < NT; ++c){
#pragma unroll
        for (int reg = 0; reg < 4; ++reg){
            int row = rowBase + oct * 4 + reg;
            if (row < M){
                int col = c * 16 + r;
                float v = acc[c][reg];
                if (C)   C[(size_t)row * Ncol + col] = v;
                if (Cbf) Cbf[(size_t)row * Ncol + col] = f2bf(v);
            }
        }
    }

    // ---- fused node-alpha
    float as_v[NT], ad_v[NT];
#pragma unroll
    for (int c = 0; c < NT; ++c){
        as_v[c] = a_s[c * 16 + r];
        ad_v[c] = a_d[c * 16 + r];
    }
    float vs[HH * 4], vd[HH * 4];
#pragma unroll
    for (int h = 0; h < HH; ++h)
#pragma unroll
        for (int reg = 0; reg < 4; ++reg){
            vs[h * 4 + reg] = acc[2 * h][reg] * as_v[2 * h]
                            + acc[2 * h + 1][reg] * as_v[2 * h + 1];
            vd[h * 4 + reg] = acc[2 * h][reg] * ad_v[2 * h]
                            + acc[2 * h + 1][reg] * ad_v[2 * h + 1];
        }
#pragma unroll
    for (int off = 1; off < 16; off <<= 1){
#pragma unroll
        for (int k = 0; k < HH * 4; ++k){
            vs[k] += __shfl_xor(vs[k], off);
            vd[k] += __shfl_xor(vd[k], off);
        }
    }
    if (HH == 4){
        // lane r (0..15): head = r>>2, reg = r&3 — one asrc + one adst store
        int reg = r & 3, hd = r >> 2;
        int row = rowBase + oct * 4 + reg;
        if (row < M){
            asrc[row * 4 + hd] = vs[hd * 4 + reg];
            adst[row * 4 + hd] = vd[hd * 4 + reg];
        }
    } else {
        int reg = r & 3;
        int row = rowBase + oct * 4 + reg;
        if (row < M){
            if (r < 4)       asrc[row] = vs[reg];
            else if (r < 8)  adst[row] = vd[reg];
        }
    }
}

// ---------- SINGLE-PASS aggregation, 4 heads x 32 ch (bf16 h)  [round-7]
// 4 edge subgroups x 16 chunk-lanes; adjacent-pair edges (8 edges/wave-iter).
__global__ __launch_bounds__(256) void k_agg4s(
        const uint4* __restrict__ hb4,            // [NN][16] dwordx4 bf16 rows
        const float* __restrict__ asrc, const float* __restrict__ adst,
        const int* __restrict__ row_ptr, const unsigned short* __restrict__ ssrc,
        const float* __restrict__ bias, float* __restrict__ outp,
        float* __restrict__ gdenom, int writeStats){
    int wave = (blockIdx.x * 256 + threadIdx.x) >> 6;
    int lane = threadIdx.x & 63;
    if (wave >= NN) return;
    int i = wave;
    int lo = row_ptr[i], hi = row_ptr[i + 1];
    int g = lane >> 4;                   // edge subgroup 0..3
    int q = lane & 15;                   // channel chunk: ch q*8..q*8+7
    int myh = q >> 2;                    // head of these channels
    float adv = adst[i * 4 + myh];

    float acc[8];
#pragma unroll
    for (int k = 0; k < 8; ++k) acc[k] = 0.f;
    float dsum = 0.f;

#define AGG4_FMA(AA, GV) {                                                    \
        acc[0] += (AA) * __uint_as_float((GV).x << 16);                       \
        acc[1] += (AA) * __uint_as_float((GV).x & 0xffff0000u);               \
        acc[2] += (AA) * __uint_as_float((GV).y << 16);                       \
        acc[3] += (AA) * __uint_as_float((GV).y & 0xffff0000u);               \
        acc[4] += (AA) * __uint_as_float((GV).z << 16);                       \
        acc[5] += (AA) * __uint_as_float((GV).z & 0xffff0000u);               \
        acc[6] += (AA) * __uint_as_float((GV).w << 16);                       \
        acc[7] += (AA) * __uint_as_float((GV).w & 0xffff0000u); }
#define AGG4_ONE(JJ) {                                                        \
        float lg_ = asrc[(JJ) * 4u + myh] + adv;                              \
        lg_ = fmaxf(lg_, NEG * lg_);                                          \
        float a_ = __expf(lg_);                                               \
        dsum += a_;                                                           \
        uint4 gv_ = hb4[(JJ) * 16u + (unsigned)q];                            \
        AGG4_FMA(a_, gv_) }

    int idx = lo;
    if (lo & 1){                         // peel to even alignment
        if (g == 0){ unsigned j = ssrc[lo]; AGG4_ONE(j) }
        idx = lo + 1;
    }
    for (; idx + 8 <= hi; idx += 8){
        unsigned pair = *(const unsigned*)&ssrc[idx + 2 * g];   // aligned
        unsigned j0 = pair & 0xffffu, j1 = pair >> 16;
        float s0 = asrc[j0 * 4u + myh];
        float s1 = asrc[j1 * 4u + myh];
        uint4 gv0 = hb4[j0 * 16u + (unsigned)q];
        uint4 gv1 = hb4[j1 * 16u + (unsigned)q];
        float lg0 = s0 + adv; lg0 = fmaxf(lg0, NEG * lg0);
        float lg1 = s1 + adv; lg1 = fmaxf(lg1, NEG * lg1);
        float a0 = __expf(lg0), a1 = __expf(lg1);
        dsum += a0 + a1;
        AGG4_FMA(a0, gv0)
        AGG4_FMA(a1, gv1)
    }
    {   // remainder < 8 edges
        int k0 = idx + 2 * g, k1 = k0 + 1;
        if (k0 < hi){ unsigned j = ssrc[k0]; AGG4_ONE(j) }
        if (k1 < hi){ unsigned j = ssrc[k1]; AGG4_ONE(j) }
    }
#undef AGG4_ONE
#undef AGG4_FMA
    // combine the 4 edge subgroups (lane bits 4,5), q stays fixed
#pragma unroll
    for (int k = 0; k < 8; ++k){
        acc[k] += __shfl_xor(acc[k], 16);
        acc[k] += __shfl_xor(acc[k], 32);
    }
    dsum += __shfl_xor(dsum, 16);
    dsum += __shfl_xor(dsum, 32);

    if (writeStats && g == 0 && (q & 3) == 0)
        gdenom[i * 4 + myh] = dsum;

    if (g == 0){
        float rs = 1.f / dsum;
        int c0 = q * 8;
        float4 bA = *(const float4*)&bias[c0];
        float4 bB = *(const float4*)&bias[c0 + 4];
        float o[8] = {acc[0] * rs + bA.x, acc[1] * rs + bA.y,
                      acc[2] * rs + bA.z, acc[3] * rs + bA.w,
                      acc[4] * rs + bB.x, acc[5] * rs + bB.y,
                      acc[6] * rs + bB.z, acc[7] * rs + bB.w};
#pragma unroll
        for (int k = 0; k < 8; ++k)
            o[k] = (o[k] > 0.f) ? o[k] : (__expf(o[k]) - 1.f);   // ELU
        *(float4*)&outp[(size_t)i * 128 + c0]     = make_float4(o[0], o[1], o[2], o[3]);
        *(float4*)&outp[(size_t)i * 128 + c0 + 4] = make_float4(o[4], o[5], o[6], o[7]);
    }
}

// ------------------------------------ alpha0 in ORIGINAL edge order (layer0)
__global__ void k_alpha0(const int* __restrict__ ei, int E,
                         const float4* __restrict__ asrc4, const float4* __restrict__ adst4,
                         const float4* __restrict__ gd4, float4* __restrict__ out){
    int e = blockIdx.x * 256 + threadIdx.x;
    int EP = E + NN;
    if (e >= EP) return;
    int s, d;
    if (e < E){ s = ei[e]; d = ei[E + e]; } else { s = e - E; d = s; }
    float4 as = asrc4[s], ad = adst4[d], dn = gd4[d];
    float4 r;
    float lg;
    lg = as.x + ad.x; lg = fmaxf(lg, NEG * lg); r.x = __expf(lg) / dn.x;
    lg = as.y + ad.y; lg = fmaxf(lg, NEG * lg); r.y = __expf(lg) / dn.y;
    lg = as.z + ad.z; lg = fmaxf(lg, NEG * lg); r.z = __expf(lg) / dn.z;
    lg = as.w + ad.w; lg = fmaxf(lg, NEG * lg); r.w = __expf(lg) / dn.w;
    out[e] = r;
}

// ---------- SINGLE-PASS aggregation, 1 head x 32 ch (fp32 h)  [round-7]
// 8 subgroups x 8 chunk-lanes; adjacent-pair edges (16 edges/wave-iter).
__global__ __launch_bounds__(256) void k_agg1s(
        const float4* __restrict__ h24,           // [NN][8] float4 rows
        const float* __restrict__ asrc, const float* __restrict__ adst,
        const int* __restrict__ row_ptr, const unsigned short* __restrict__ ssrc,
        const float* __restrict__ bias, float* __restrict__ outp){
    int wave = (blockIdx.x * 256 + threadIdx.x) >> 6;
    int lane = threadIdx.x & 63;
    if (wave >= NN) return;
    int i = wave;
    int lo = row_ptr[i], hi = row_ptr[i + 1];
    int g = lane >> 3;                   // edge subgroup 0..7
    int q = lane & 7;                    // channel chunk: ch q*4..q*4+3
    float adv = adst[i];

    float acc[4] = {0.f, 0.f, 0.f, 0.f};
    float dsum = 0.f;

#define AGG1_ONE(JJ) {                                                        \
        float lg_ = asrc[(JJ)] + adv;                                         \
        lg_ = fmaxf(lg_, NEG * lg_);                                          \
        float a_ = __expf(lg_);                                               \
        dsum += a_;                                                           \
        float4 v_ = h24[(JJ) * 8u + (unsigned)q];                             \
        acc[0] += a_ * v_.x; acc[1] += a_ * v_.y;                             \
        acc[2] += a_ * v_.z; acc[3] += a_ * v_.w; }

    int idx = lo;
    if (lo & 1){
        if (g == 0){ unsigned j = ssrc[lo]; AGG1_ONE(j) }
        idx = lo + 1;
    }
    for (; idx + 16 <= hi; idx += 16){
        unsigned pair = *(const unsigned*)&ssrc[idx + 2 * g];
        unsigned j0 = pair & 0xffffu, j1 = pair >> 16;
        float s0 = asrc[j0];
        float s1 = asrc[j1];
        float4 v0 = h24[j0 * 8u + (unsigned)q];
        float4 v1 = h24[j1 * 8u + (unsigned)q];
        float lg0 = s0 + adv; lg0 = fmaxf(lg0, NEG * lg0);
        float lg1 = s1 + adv; lg1 = fmaxf(lg1, NEG * lg1);
        float a0 = __expf(lg0), a1 = __expf(lg1);
        dsum += a0 + a1;
        acc[0] += a0 * v0.x; acc[1] += a0 * v0.y;
        acc[2] += a0 * v0.z; acc[3] += a0 * v0.w;
        acc[0] += a1 * v1.x; acc[1] += a1 * v1.y;
        acc[2] += a1 * v1.z; acc[3] += a1 * v1.w;
    }
    {   // remainder < 16 edges
        int k0 = idx + 2 * g, k1 = k0 + 1;
        if (k0 < hi){ unsigned j = ssrc[k0]; AGG1_ONE(j) }
        if (k1 < hi){ unsigned j = ssrc[k1]; AGG1_ONE(j) }
    }
#undef AGG1_ONE
#pragma unroll
    for (int k = 0; k < 4; ++k){
        acc[k] += __shfl_xor(acc[k], 8);
        acc[k] += __shfl_xor(acc[k], 16);
        acc[k] += __shfl_xor(acc[k], 32);
    }
    dsum += __shfl_xor(dsum, 8);
    dsum += __shfl_xor(dsum, 16);
    dsum += __shfl_xor(dsum, 32);
    if (g == 0){
        float rs = 1.f / dsum;
        float4 b = *(const float4*)&bias[q * 4];
        *(float4*)&outp[(size_t)i * 32 + q * 4] =
            make_float4(acc[0] * rs + b.x, acc[1] * rs + b.y,
                        acc[2] * rs + b.z, acc[3] * rs + b.w);
    }
}

// ---------------------------------------------------------------- launcher
extern "C" void kernel_launch(void* const* d_in, const int* in_sizes, int n_in,
                              void* d_out, int out_size, void* d_ws, size_t ws_size,
                              hipStream_t stream){
    const float* x   = (const float*)d_in[0];
    const int*   ei  = (const int*)  d_in[1];
    const float* W0  = (const float*)d_in[2];
    const float* as0 = (const float*)d_in[3];
    const float* ad0 = (const float*)d_in[4];
    const float* b0  = (const float*)d_in[5];
    const float* W1  = (const float*)d_in[6];
    const float* as1 = (const float*)d_in[7];
    const float* ad1 = (const float*)d_in[8];
    const float* b1  = (const float*)d_in[9];
    const float* W2  = (const float*)d_in[10];
    const float* as2 = (const float*)d_in[11];
    const float* ad2 = (const float*)d_in[12];
    const float* b2  = (const float*)d_in[13];

    const int E  = in_sizes[1] / 2;
    const int EP = E + NN;

    char* w = (char*)d_ws;
    size_t off = 0;
    auto carve = [&](size_t bytes) -> char* {
        char* p = w + off;
        off += (bytes + 255) & ~(size_t)255;
        return p;
    };
    int*            bucketCount = (int*)       carve(sizeof(int) * 256);
    int*            row_ptr = (int*)           carve(sizeof(int) * (NN + 1));
    unsigned short* ssrc    = (unsigned short*)carve(sizeof(short) * ((size_t)EP + 2));
    float*          hbuf    = (float*)         carve(sizeof(float) * (size_t)NN * 32);
    unsigned short* hb16    = (unsigned short*)carve(sizeof(short) * (size_t)NN * 128);
    float*          post    = (float*)         carve(sizeof(float) * (size_t)NN * 128);
    float*          asrc    = (float*)         carve(sizeof(float) * NN * 4);
    float*          adst    = (float*)         carve(sizeof(float) * NN * 4);
    float*          gdenom  = (float*)         carve(sizeof(float) * NN * 4);
    unsigned short* Whi0    = (unsigned short*)carve(sizeof(short) * 16384);
    unsigned short* Wlo0    = (unsigned short*)carve(sizeof(short) * 16384);
    unsigned short* Whi1    = (unsigned short*)carve(sizeof(short) * 16384);
    unsigned short* Wlo1    = (unsigned short*)carve(sizeof(short) * 16384);
    unsigned short* Whi2    = (unsigned short*)carve(sizeof(short) * 4096);
    unsigned short* Wlo2    = (unsigned short*)carve(sizeof(short) * 4096);
    // tmp (16MB) aliases post (25.6MB): consumed by k_bucket_csr before
    // layer-0 agg4s first writes post (stream-ordered).
    unsigned*       tmp     = (unsigned*)post;

    float* out_alpha = (float*)d_out;                  // [EP, 4]
    float* out_final = (float*)d_out + (size_t)EP * 4; // [NN, 32]

    const int edgeBlocks = (EP + 255) / 256;
    const int waveBlocks = (NN + 3) / 4;
    const int gemmBlocks = (NN + 63) / 64;

    // ---- CSR build + weight pack
    hipMemsetAsync(bucketCount, 0, sizeof(int) * 256, stream);
    k_binning   <<<(EP + TILE - 1) / TILE, 256, 0, stream>>>(ei, E, bucketCount, tmp);
    k_bucket_csr<<<256, 256, 0, stream>>>(EP, bucketCount, tmp, row_ptr, ssrc);
    k_packW     <<<144, 256, 0, stream>>>(W0, W1, W2, Whi0, Wlo0, Whi1, Wlo1, Whi2, Wlo2);

    // ---- layer 0 (GEMM + fused node-alpha; fp32 C dead -> skipped)
    k_gemm_mfma<8, 4><<<gemmBlocks, 256, 0, stream>>>(x, Whi0, Wlo0,
        nullptr, hb16, as0, ad0, asrc, adst, NN);
    k_agg4s<<<waveBlocks, 256, 0, stream>>>((const uint4*)hb16, asrc, adst, row_ptr,
                                            ssrc, b0, post, gdenom, 1);
    k_alpha0<<<edgeBlocks, 256, 0, stream>>>(ei, E, (const float4*)asrc, (const float4*)adst,
                                             (const float4*)gdenom, (float4*)out_alpha);

    // ---- layer 1
    k_gemm_mfma<8, 4><<<gemmBlocks, 256, 0, stream>>>(post, Whi1, Wlo1,
        nullptr, hb16, as1, ad1, asrc, adst, NN);
    k_agg4s<<<waveBlocks, 256, 0, stream>>>((const uint4*)hb16, asrc, adst, row_ptr,
                                            ssrc, b1, post, gdenom, 0);

    // ---- layer 2 (1 head, 32 out, no concat/ELU; fp32 C kept for agg1s)
    k_gemm_mfma<2, 1><<<gemmBlocks, 256, 0, stream>>>(post, Whi2, Wlo2,
        hbuf, nullptr, as2, ad2, asrc, adst, NN);
    k_agg1s<<<waveBlocks, 256, 0, stream>>>((const float4*)hbuf, asrc, adst, row_ptr,
                                            ssrc, b2, out_final);
}